// Round 3
// baseline (208.124 us; speedup 1.0000x reference)
//
#include <hip/hip_runtime.h>
#include <hip/hip_bf16.h>

#define BB 16
#define NC 64
#define NP 384
#define HH 128
#define CF 56
#define PFT 1280

typedef float f32x4 __attribute__((ext_vector_type(4)));
typedef __bf16 bf16x8 __attribute__((ext_vector_type(8)));
typedef unsigned short u16x8 __attribute__((ext_vector_type(8)));

static __device__ __forceinline__ unsigned short f2bfu(float f){
  __bf16 h = (__bf16)f;
  return __builtin_bit_cast(unsigned short, h);
}
static __device__ __forceinline__ float bfu2f(unsigned short u){
  __bf16 h = __builtin_bit_cast(__bf16, u);
  return (float)h;
}

// ---------------- compound linear + LN -> bf16 (to ws) ----------------
__global__ __launch_bounds__(128) void k_comp_emb(
    const float* __restrict__ cf, const float* __restrict__ Wc,
    const float* __restrict__ bc, const float* __restrict__ lng,
    const float* __restrict__ lnb, unsigned short* __restrict__ c_ln){
  int row = blockIdx.x;
  int m = threadIdx.x;
  const float* cr = cf + row*CF;
  float acc = bc[m];
  #pragma unroll
  for (int k=0;k<CF;k++) acc += cr[k]*Wc[k*HH+m];
  float s=acc, s2=acc*acc;
  #pragma unroll
  for (int off=1; off<64; off<<=1){ s += __shfl_xor(s,off,64); s2 += __shfl_xor(s2,off,64); }
  __shared__ float red[4];
  int wid = m>>6;
  if ((m&63)==0){ red[wid*2]=s; red[wid*2+1]=s2; }
  __syncthreads();
  float S=red[0]+red[2], S2=red[1]+red[3];
  float mean = S*(1.0f/HH);
  float var  = S2*(1.0f/HH) - mean*mean;
  float rs = rsqrtf(var + 1e-5f);
  c_ln[row*HH+m] = f2bfu((acc-mean)*rs*lng[m] + lnb[m]);
}

// ---------------- pocket linear + LN -> bf16 (to ws, 8 rows/block) ----------------
__global__ __launch_bounds__(128) void k_pock_emb(
    const float* __restrict__ pf, const float* __restrict__ Wp,
    const float* __restrict__ bp, const float* __restrict__ lng,
    const float* __restrict__ lnb, unsigned short* __restrict__ p_ln){
  int row0 = blockIdx.x*8;
  int m = threadIdx.x;
  float acc[8];
  float b0 = bp[m];
  #pragma unroll
  for (int r=0;r<8;r++) acc[r]=b0;
  for (int k=0;k<PFT;k+=4){
    float w0=Wp[k*HH+m], w1=Wp[(k+1)*HH+m], w2=Wp[(k+2)*HH+m], w3=Wp[(k+3)*HH+m];
    #pragma unroll
    for (int r=0;r<8;r++){
      const float4 p4 = *(const float4*)(pf + (size_t)(row0+r)*PFT + k);
      acc[r] += p4.x*w0 + p4.y*w1 + p4.z*w2 + p4.w*w3;
    }
  }
  __shared__ float redS[8][2], redS2[8][2];
  int wid = m>>6;
  #pragma unroll
  for (int r=0;r<8;r++){
    float s=acc[r], s2=acc[r]*acc[r];
    #pragma unroll
    for (int off=1; off<64; off<<=1){ s+=__shfl_xor(s,off,64); s2+=__shfl_xor(s2,off,64); }
    if ((m&63)==0){ redS[r][wid]=s; redS2[r][wid]=s2; }
  }
  __syncthreads();
  float gm = lng[m], lb = lnb[m];
  #pragma unroll
  for (int r=0;r<8;r++){
    float S=redS[r][0]+redS[r][1], S2=redS2[r][0]+redS2[r][1];
    float mean=S*(1.0f/HH);
    float var =S2*(1.0f/HH)-mean*mean;
    float rs=rsqrtf(var+1e-5f);
    p_ln[(size_t)(row0+r)*HH+m] = f2bfu((acc[r]-mean)*rs*gm+lb);
  }
}

// ---------------- W1 (k,m) f32 -> W1^T (m,k) bf16 ----------------
__global__ void k_w1t(const float* __restrict__ W1, unsigned short* __restrict__ w1t){
  int idx = blockIdx.x*256+threadIdx.x;
  int k = idx>>7, m = idx&127;
  w1t[m*HH+k] = f2bfu(W1[idx]);
}

// ---------------- pairwise MLP: per (b, i-group of 4); float output ----------------
__global__ __launch_bounds__(128) void k_pair(
    const unsigned short* __restrict__ c_ln, const unsigned short* __restrict__ p_ln,
    const unsigned short* __restrict__ w1t, const float* __restrict__ b1,
    const float* __restrict__ W2, const float* __restrict__ b2p,
    float* __restrict__ out3){
  __shared__ __align__(16) unsigned short sC[NC*HH];   // swizzled 16B blocks
  __shared__ __align__(16) unsigned short sW[HH*HH];   // W1^T, swizzled
  __shared__ float sB1[HH], sW2[HH];
  int bx = blockIdx.x;
  int b  = bx/(NP/4);
  int i0 = (bx%(NP/4))*4;
  int tid = threadIdx.x;
  const int4* srcC = (const int4*)(c_ln + (size_t)b*NC*HH);
  for (int c=tid; c<NC*HH/8; c+=128){
    int j=c>>4, kb=c&15;
    ((int4*)sC)[j*16 + (kb^(j&7))] = srcC[c];
  }
  const int4* srcW = (const int4*)w1t;
  for (int c=tid; c<HH*HH/8; c+=128){
    int mm=c>>4, kb=c&15;
    ((int4*)sW)[mm*16 + (kb^(mm&7))] = srcW[c];
  }
  sB1[tid]=b1[tid]; sW2[tid]=W2[tid];
  __syncthreads();
  float b2 = b2p[0];
  int w = tid>>6, lane=tid&63, q=lane&15, gr=lane>>4;
  for (int ii=0; ii<4; ii++){
    int i = i0+ii;
    f32x4 acc[2][8];
    #pragma unroll
    for (int jt=0;jt<2;jt++)
      #pragma unroll
      for (int nt=0;nt<8;nt++) acc[jt][nt]=(f32x4){0.f,0.f,0.f,0.f};
    const unsigned short* prow = p_ln + (size_t)(b*NP+i)*HH;
    #pragma unroll
    for (int kt=0;kt<4;kt++){
      int kblk = kt*4+gr;                 // 16B-block index along k
      u16x8 pv = *(const u16x8*)(prow + kblk*8);
      float pk[8];
      #pragma unroll
      for (int e=0;e<8;e++) pk[e]=bfu2f(pv[e]);
      bf16x8 a[2];
      #pragma unroll
      for (int jt=0;jt<2;jt++){
        int j=(w*2+jt)*16+q;
        u16x8 cv = *(const u16x8*)&sC[j*HH + ((kblk^(j&7))<<3)];
        #pragma unroll
        for (int e=0;e<8;e++) a[jt][e] = (__bf16)(bfu2f(cv[e])*pk[e]);
      }
      #pragma unroll
      for (int nt=0;nt<8;nt++){
        int mm=nt*16+q;
        bf16x8 bv = __builtin_bit_cast(bf16x8, *(const u16x8*)&sW[mm*HH + ((kblk^(mm&7))<<3)]);
        acc[0][nt]=__builtin_amdgcn_mfma_f32_16x16x32_bf16(a[0],bv,acc[0][nt],0,0,0);
        acc[1][nt]=__builtin_amdgcn_mfma_f32_16x16x32_bf16(a[1],bv,acc[1][nt],0,0,0);
      }
    }
    float part[2][4]={{0.f,0.f,0.f,0.f},{0.f,0.f,0.f,0.f}};
    #pragma unroll
    for (int nt=0;nt<8;nt++){
      float b1v=sB1[nt*16+q], w2v=sW2[nt*16+q];
      #pragma unroll
      for (int jt=0;jt<2;jt++)
        #pragma unroll
        for (int r=0;r<4;r++){
          float h=acc[jt][nt][r]+b1v;
          h = h>0.f?h:0.f;
          part[jt][r] += h*w2v;
        }
    }
    float* orow = out3 + (size_t)(b*NP+i)*NC;
    #pragma unroll
    for (int jt=0;jt<2;jt++)
      #pragma unroll
      for (int r=0;r<4;r++){
        float v=part[jt][r];
        v += __shfl_xor(v,1,64); v+=__shfl_xor(v,2,64);
        v += __shfl_xor(v,4,64); v+=__shfl_xor(v,8,64);
        if (q==0){
          float lg=v+b2;
          orow[(w*2+jt)*16+gr*4+r]=10.f/(1.f+expf(-lg));
        }
      }
  }
}

// ---------------- coords + batch ids (float out) ----------------
__global__ void k_misc(const float* __restrict__ cc, float* __restrict__ out){
  int idx = blockIdx.x*256+threadIdx.x;
  if (idx < BB*NC*3){
    int bb = idx/(NC*3), rem = idx%(NC*3);
    float v = cc[(size_t)bb*(2+NC+NP)*3 + 3 + rem];
    out[idx] = (v/5.0f)*5.0f;
  }
  if (idx < BB*NC) out[BB*NC*3+idx] = (float)(idx>>6);
}

// ---------------- pc_dis + dis_map passthrough (float out) ----------------
__global__ void k_dis(const float* __restrict__ px, const float* __restrict__ cc,
                      const float* __restrict__ dm, float* __restrict__ out4,
                      float* __restrict__ out5){
  int idx = blockIdx.x*256+threadIdx.x;
  if (idx >= BB*NP*NC) return;
  int b = idx/(NP*NC), r = idx%(NP*NC), i = r>>6, j = r&63;
  const float* pp = px + ((size_t)b*NP+i)*3;
  const float* cp = cc + (size_t)b*(2+NC+NP)*3 + 3 + (size_t)j*3;
  float dx=pp[0]/5.0f-cp[0]/5.0f;
  float dy=pp[1]/5.0f-cp[1]/5.0f;
  float dz=pp[2]/5.0f-cp[2]/5.0f;
  float d = sqrtf(dx*dx+dy*dy+dz*dz)*5.0f;
  d = fminf(fmaxf(d,0.f),10.f);
  out4[idx]=d;
  out5[idx]=dm[idx];
}

extern "C" void kernel_launch(void* const* d_in, const int* in_sizes, int n_in,
                              void* d_out, int out_size, void* d_ws, size_t ws_size,
                              hipStream_t stream){
  const float* cf = (const float*)d_in[0];
  const float* pf = (const float*)d_in[1];
  const float* cc = (const float*)d_in[2];
  const float* px = (const float*)d_in[3];
  const float* dm = (const float*)d_in[4];
  const float* Wc = (const float*)d_in[5];
  const float* bc = (const float*)d_in[6];
  const float* Wp = (const float*)d_in[7];
  const float* bp = (const float*)d_in[8];
  const float* lng= (const float*)d_in[9];
  const float* lnb= (const float*)d_in[10];
  const float* W1 = (const float*)d_in[11];
  const float* b1 = (const float*)d_in[12];
  const float* W2 = (const float*)d_in[13];
  const float* b2 = (const float*)d_in[14];

  float* out = (float*)d_out;
  char* ws = (char*)d_ws;
  unsigned short* c_ln = (unsigned short*)ws;                      // 1024*128*2 = 262144 B
  unsigned short* p_ln = (unsigned short*)(ws + 262144);           // 6144*128*2 = 1572864 B
  unsigned short* w1t  = (unsigned short*)(ws + 262144 + 1572864); // 128*128*2  = 32768 B

  float* out1 = out;                       // 3072 coords
  float* out3 = out + BB*NC*3 + BB*NC;     // +1024 batch -> 4096
  float* out4 = out3 + BB*NP*NC;           // sigmoid pairs
  float* out5 = out4 + BB*NP*NC;           // pc_dis, then dis_map

  hipLaunchKernelGGL(k_comp_emb, dim3(BB*NC),    dim3(128), 0, stream, cf, Wc, bc, lng, lnb, c_ln);
  hipLaunchKernelGGL(k_pock_emb, dim3(BB*NP/8),  dim3(128), 0, stream, pf, Wp, bp, lng, lnb, p_ln);
  hipLaunchKernelGGL(k_w1t,      dim3(64),       dim3(256), 0, stream, W1, w1t);
  hipLaunchKernelGGL(k_pair,     dim3(BB*NP/4),  dim3(128), 0, stream, c_ln, p_ln, w1t, b1, W2, b2, out3);
  hipLaunchKernelGGL(k_misc,     dim3(12),       dim3(256), 0, stream, cc, out1);
  hipLaunchKernelGGL(k_dis,      dim3(BB*NP*NC/256), dim3(256), 0, stream, px, cc, dm, out4, out5);
}

// Round 4
// 94.724 us; speedup vs baseline: 2.1972x; 2.1972x over previous
//
#include <hip/hip_runtime.h>
#include <hip/hip_bf16.h>

#define BB 16
#define NC 64
#define NP 384
#define HH 128
#define CF 56
#define PFT 1280

typedef float f32x4 __attribute__((ext_vector_type(4)));
typedef __bf16 bf16x8 __attribute__((ext_vector_type(8)));
typedef unsigned short u16x8 __attribute__((ext_vector_type(8)));
typedef unsigned short u16x4 __attribute__((ext_vector_type(4)));

static __device__ __forceinline__ unsigned short f2bfu(float f){
  __bf16 h = (__bf16)f;
  return __builtin_bit_cast(unsigned short, h);
}
static __device__ __forceinline__ float bfu2f(unsigned short u){
  __bf16 h = __builtin_bit_cast(__bf16, u);
  return (float)h;
}

// ---------------- compound linear + LN -> bf16 (to ws) ----------------
__global__ __launch_bounds__(128) void k_comp_emb(
    const float* __restrict__ cf, const float* __restrict__ Wc,
    const float* __restrict__ bc, const float* __restrict__ lng,
    const float* __restrict__ lnb, unsigned short* __restrict__ c_ln){
  int row = blockIdx.x;
  int m = threadIdx.x;
  const float* cr = cf + row*CF;
  float acc = bc[m];
  #pragma unroll
  for (int k=0;k<CF;k++) acc += cr[k]*Wc[k*HH+m];
  float s=acc, s2=acc*acc;
  #pragma unroll
  for (int off=1; off<64; off<<=1){ s += __shfl_xor(s,off,64); s2 += __shfl_xor(s2,off,64); }
  __shared__ float red[4];
  int wid = m>>6;
  if ((m&63)==0){ red[wid*2]=s; red[wid*2+1]=s2; }
  __syncthreads();
  float S=red[0]+red[2], S2=red[1]+red[3];
  float mean = S*(1.0f/HH);
  float var  = S2*(1.0f/HH) - mean*mean;
  float rs = rsqrtf(var + 1e-5f);
  c_ln[row*HH+m] = f2bfu((acc-mean)*rs*lng[m] + lnb[m]);
}

// ---------------- Wp f32 [1280][128] -> WpT bf16 [128][1280] ----------------
__global__ __launch_bounds__(256) void k_wpt(const float* __restrict__ Wp,
                                             unsigned short* __restrict__ wpt){
  __shared__ unsigned short t[128][72];   // [col][k-chunk], padded
  int k0 = blockIdx.x*64;
  int tid = threadIdx.x;
  #pragma unroll
  for (int i=0;i<8;i++){
    int fi = tid + i*256;                 // 0..2047 float4 over 64k x 128col
    int k  = fi>>5;                        // 32 float4 per k-row
    int c4 = (fi&31)*4;
    float4 v = *(const float4*)(Wp + (size_t)(k0+k)*HH + c4);
    t[c4+0][k]=f2bfu(v.x); t[c4+1][k]=f2bfu(v.y);
    t[c4+2][k]=f2bfu(v.z); t[c4+3][k]=f2bfu(v.w);
  }
  __syncthreads();
  #pragma unroll
  for (int i=0;i<4;i++){
    int ci = tid + i*256;                 // 0..1023 16B chunks
    int col = ci>>3, kb = ci&7;
    u16x8 v = *(const u16x8*)&t[col][kb*8];
    *(u16x8*)(wpt + (size_t)col*PFT + k0 + kb*8) = v;
  }
}

// ------- pocket GEMM [6144,1280]x[1280,128] + bias + LN -> bf16 p_ln -------
// BM=32 rows/block, 4 waves: waves {0,1}=K[0,640), {2,3}=K[640,1280);
// within pair, wave handles 16 rows. Split-K combined via LDS, LN fused.
__global__ __launch_bounds__(256) void k_pock(
    const float* __restrict__ pf, const unsigned short* __restrict__ wpt,
    const float* __restrict__ bp, const float* __restrict__ lng,
    const float* __restrict__ lnb, unsigned short* __restrict__ p_ln){
  __shared__ __align__(16) unsigned short sA[2][32*64];    // 4KB each, swizzled
  __shared__ __align__(16) unsigned short sB[2][HH*64];    // 16KB each, swizzled
  __shared__ float sBp[HH], sG[HH], sBl[HH];
  int tid = threadIdx.x;
  int w = tid>>6, lane = tid&63, q = lane&15, gr = lane>>4;
  int pair = w>>1, rh = w&1;
  int tp = tid & 127;
  int row0 = blockIdx.x*32;
  if (tid < HH){ sBp[tid]=bp[tid]; sG[tid]=lng[tid]; sBl[tid]=lnb[tid]; }
  f32x4 acc[8];
  #pragma unroll
  for (int nt=0;nt<8;nt++) acc[nt]=(f32x4){0.f,0.f,0.f,0.f};
  char* A = (char*)&sA[pair][0];
  char* Bc = (char*)&sB[pair][0];
  int khalf0 = pair*640;
  int rowl = rh*16 + q;                    // A-tile row this lane reads
  for (int ks=0; ks<10; ks++){
    int kbase = khalf0 + ks*64;
    __syncthreads();
    // stage A: 32 rows x 64 k f32 -> bf16, 512 float4, 4 per thread-of-pair
    #pragma unroll
    for (int i=0;i<4;i++){
      int fi = tp + 128*i;
      int row = fi>>4;
      int k4  = (fi&15)*4;
      float4 v = *(const float4*)(pf + (size_t)(row0+row)*PFT + kbase + k4);
      u16x4 h = { f2bfu(v.x), f2bfu(v.y), f2bfu(v.z), f2bfu(v.w) };
      *(u16x4*)(A + row*128 + (((k4>>3)^(row&7))<<4) + ((k4&7)<<1)) = h;
    }
    // stage B: 128 col x 64 k bf16, 1024 16B chunks, 8 per thread-of-pair
    #pragma unroll
    for (int i=0;i<8;i++){
      int bi = tp + 128*i;
      int col = bi>>3, kb = bi&7;
      u16x8 v = *(const u16x8*)(wpt + (size_t)col*PFT + kbase + kb*8);
      *(u16x8*)(Bc + col*128 + ((kb^(col&7))<<4)) = v;
    }
    __syncthreads();
    #pragma unroll
    for (int kk=0;kk<2;kk++){
      bf16x8 a = *(bf16x8*)(A + rowl*128 + (((kk*4+gr)^(rowl&7))<<4));
      #pragma unroll
      for (int nt=0;nt<8;nt++){
        int col = nt*16+q;
        bf16x8 b = *(bf16x8*)(Bc + col*128 + (((kk*4+gr)^(col&7))<<4));
        acc[nt] = __builtin_amdgcn_mfma_f32_16x16x32_bf16(a,b,acc[nt],0,0,0);
      }
    }
  }
  __syncthreads();
  float* comb = (float*)&sB[0][0];         // 32x128 f32 = 16KB
  if (pair==1){
    #pragma unroll
    for (int nt=0;nt<8;nt++)
      #pragma unroll
      for (int r=0;r<4;r++)
        comb[(rh*16+gr*4+r)*HH + nt*16+q] = acc[nt][r];
  }
  __syncthreads();
  if (pair==0){
    float v[8][4];
    #pragma unroll
    for (int nt=0;nt<8;nt++){
      float bpv = sBp[nt*16+q];
      #pragma unroll
      for (int r=0;r<4;r++)
        v[nt][r] = acc[nt][r] + comb[(rh*16+gr*4+r)*HH + nt*16+q] + bpv;
    }
    #pragma unroll
    for (int r=0;r<4;r++){
      float s=0.f, s2=0.f;
      #pragma unroll
      for (int nt=0;nt<8;nt++){ s += v[nt][r]; s2 += v[nt][r]*v[nt][r]; }
      s  += __shfl_xor(s,1,64);  s2 += __shfl_xor(s2,1,64);
      s  += __shfl_xor(s,2,64);  s2 += __shfl_xor(s2,2,64);
      s  += __shfl_xor(s,4,64);  s2 += __shfl_xor(s2,4,64);
      s  += __shfl_xor(s,8,64);  s2 += __shfl_xor(s2,8,64);
      float mean = s*(1.0f/HH);
      float var  = s2*(1.0f/HH) - mean*mean;
      float rs   = rsqrtf(var + 1e-5f);
      int row = row0 + rh*16 + gr*4 + r;
      #pragma unroll
      for (int nt=0;nt<8;nt++){
        int col = nt*16+q;
        p_ln[(size_t)row*HH + col] = f2bfu((v[nt][r]-mean)*rs*sG[col] + sBl[col]);
      }
    }
  }
}

// ---------------- W1 (k,m) f32 -> W1^T (m,k) bf16 ----------------
__global__ void k_w1t(const float* __restrict__ W1, unsigned short* __restrict__ w1t){
  int idx = blockIdx.x*256+threadIdx.x;
  int k = idx>>7, m = idx&127;
  w1t[m*HH+k] = f2bfu(W1[idx]);
}

// ---------------- pairwise MLP: per (b, i-group of 4); float output ----------------
__global__ __launch_bounds__(128) void k_pair(
    const unsigned short* __restrict__ c_ln, const unsigned short* __restrict__ p_ln,
    const unsigned short* __restrict__ w1t, const float* __restrict__ b1,
    const float* __restrict__ W2, const float* __restrict__ b2p,
    float* __restrict__ out3){
  __shared__ __align__(16) unsigned short sC[NC*HH];   // swizzled 16B blocks
  __shared__ __align__(16) unsigned short sW[HH*HH];   // W1^T, swizzled
  __shared__ float sB1[HH], sW2[HH];
  int bx = blockIdx.x;
  int b  = bx/(NP/4);
  int i0 = (bx%(NP/4))*4;
  int tid = threadIdx.x;
  const int4* srcC = (const int4*)(c_ln + (size_t)b*NC*HH);
  for (int c=tid; c<NC*HH/8; c+=128){
    int j=c>>4, kb=c&15;
    ((int4*)sC)[j*16 + (kb^(j&7))] = srcC[c];
  }
  const int4* srcW = (const int4*)w1t;
  for (int c=tid; c<HH*HH/8; c+=128){
    int mm=c>>4, kb=c&15;
    ((int4*)sW)[mm*16 + (kb^(mm&7))] = srcW[c];
  }
  sB1[tid]=b1[tid]; sW2[tid]=W2[tid];
  __syncthreads();
  float b2 = b2p[0];
  int w = tid>>6, lane=tid&63, q=lane&15, gr=lane>>4;
  for (int ii=0; ii<4; ii++){
    int i = i0+ii;
    f32x4 acc[2][8];
    #pragma unroll
    for (int jt=0;jt<2;jt++)
      #pragma unroll
      for (int nt=0;nt<8;nt++) acc[jt][nt]=(f32x4){0.f,0.f,0.f,0.f};
    const unsigned short* prow = p_ln + (size_t)(b*NP+i)*HH;
    #pragma unroll
    for (int kt=0;kt<4;kt++){
      int kblk = kt*4+gr;
      u16x8 pv = *(const u16x8*)(prow + kblk*8);
      float pk[8];
      #pragma unroll
      for (int e=0;e<8;e++) pk[e]=bfu2f(pv[e]);
      bf16x8 a[2];
      #pragma unroll
      for (int jt=0;jt<2;jt++){
        int j=(w*2+jt)*16+q;
        u16x8 cv = *(const u16x8*)&sC[j*HH + ((kblk^(j&7))<<3)];
        #pragma unroll
        for (int e=0;e<8;e++) a[jt][e] = (__bf16)(bfu2f(cv[e])*pk[e]);
      }
      #pragma unroll
      for (int nt=0;nt<8;nt++){
        int mm=nt*16+q;
        bf16x8 bv = __builtin_bit_cast(bf16x8, *(const u16x8*)&sW[mm*HH + ((kblk^(mm&7))<<3)]);
        acc[0][nt]=__builtin_amdgcn_mfma_f32_16x16x32_bf16(a[0],bv,acc[0][nt],0,0,0);
        acc[1][nt]=__builtin_amdgcn_mfma_f32_16x16x32_bf16(a[1],bv,acc[1][nt],0,0,0);
      }
    }
    float part[2][4]={{0.f,0.f,0.f,0.f},{0.f,0.f,0.f,0.f}};
    #pragma unroll
    for (int nt=0;nt<8;nt++){
      float b1v=sB1[nt*16+q], w2v=sW2[nt*16+q];
      #pragma unroll
      for (int jt=0;jt<2;jt++)
        #pragma unroll
        for (int r=0;r<4;r++){
          float h=acc[jt][nt][r]+b1v;
          h = h>0.f?h:0.f;
          part[jt][r] += h*w2v;
        }
    }
    float* orow = out3 + (size_t)(b*NP+i)*NC;
    #pragma unroll
    for (int jt=0;jt<2;jt++)
      #pragma unroll
      for (int r=0;r<4;r++){
        float v=part[jt][r];
        v += __shfl_xor(v,1,64); v+=__shfl_xor(v,2,64);
        v += __shfl_xor(v,4,64); v+=__shfl_xor(v,8,64);
        if (q==0){
          float lg=v+b2;
          orow[(w*2+jt)*16+gr*4+r]=10.f/(1.f+expf(-lg));
        }
      }
  }
}

// ---------------- coords + batch ids (float out) ----------------
__global__ void k_misc(const float* __restrict__ cc, float* __restrict__ out){
  int idx = blockIdx.x*256+threadIdx.x;
  if (idx < BB*NC*3){
    int bb = idx/(NC*3), rem = idx%(NC*3);
    float v = cc[(size_t)bb*(2+NC+NP)*3 + 3 + rem];
    out[idx] = (v/5.0f)*5.0f;
  }
  if (idx < BB*NC) out[BB*NC*3+idx] = (float)(idx>>6);
}

// ---------------- pc_dis + dis_map passthrough (float out) ----------------
__global__ void k_dis(const float* __restrict__ px, const float* __restrict__ cc,
                      const float* __restrict__ dm, float* __restrict__ out4,
                      float* __restrict__ out5){
  int idx = blockIdx.x*256+threadIdx.x;
  if (idx >= BB*NP*NC) return;
  int b = idx/(NP*NC), r = idx%(NP*NC), i = r>>6, j = r&63;
  const float* pp = px + ((size_t)b*NP+i)*3;
  const float* cp = cc + (size_t)b*(2+NC+NP)*3 + 3 + (size_t)j*3;
  float dx=pp[0]/5.0f-cp[0]/5.0f;
  float dy=pp[1]/5.0f-cp[1]/5.0f;
  float dz=pp[2]/5.0f-cp[2]/5.0f;
  float d = sqrtf(dx*dx+dy*dy+dz*dz)*5.0f;
  d = fminf(fmaxf(d,0.f),10.f);
  out4[idx]=d;
  out5[idx]=dm[idx];
}

extern "C" void kernel_launch(void* const* d_in, const int* in_sizes, int n_in,
                              void* d_out, int out_size, void* d_ws, size_t ws_size,
                              hipStream_t stream){
  const float* cf = (const float*)d_in[0];
  const float* pf = (const float*)d_in[1];
  const float* cc = (const float*)d_in[2];
  const float* px = (const float*)d_in[3];
  const float* dm = (const float*)d_in[4];
  const float* Wc = (const float*)d_in[5];
  const float* bc = (const float*)d_in[6];
  const float* Wp = (const float*)d_in[7];
  const float* bp = (const float*)d_in[8];
  const float* lng= (const float*)d_in[9];
  const float* lnb= (const float*)d_in[10];
  const float* W1 = (const float*)d_in[11];
  const float* b1 = (const float*)d_in[12];
  const float* W2 = (const float*)d_in[13];
  const float* b2 = (const float*)d_in[14];

  float* out = (float*)d_out;
  char* ws = (char*)d_ws;
  unsigned short* c_ln = (unsigned short*)ws;                      // 262144 B
  unsigned short* p_ln = (unsigned short*)(ws + 262144);           // 1572864 B
  unsigned short* w1t  = (unsigned short*)(ws + 262144 + 1572864); // 32768 B
  unsigned short* wpt  = (unsigned short*)(ws + 262144 + 1572864 + 32768); // 1280*128*2 = 327680 B

  float* out1 = out;
  float* out3 = out + BB*NC*3 + BB*NC;
  float* out4 = out3 + BB*NP*NC;
  float* out5 = out4 + BB*NP*NC;

  hipLaunchKernelGGL(k_comp_emb, dim3(BB*NC),    dim3(128), 0, stream, cf, Wc, bc, lng, lnb, c_ln);
  hipLaunchKernelGGL(k_wpt,      dim3(PFT/64),   dim3(256), 0, stream, Wp, wpt);
  hipLaunchKernelGGL(k_pock,     dim3(BB*NP/32), dim3(256), 0, stream, pf, wpt, bp, lng, lnb, p_ln);
  hipLaunchKernelGGL(k_w1t,      dim3(64),       dim3(256), 0, stream, W1, w1t);
  hipLaunchKernelGGL(k_pair,     dim3(BB*NP/4),  dim3(128), 0, stream, c_ln, p_ln, w1t, b1, W2, b2, out3);
  hipLaunchKernelGGL(k_misc,     dim3(12),       dim3(256), 0, stream, cc, out1);
  hipLaunchKernelGGL(k_dis,      dim3(BB*NP*NC/256), dim3(256), 0, stream, px, cc, dm, out4, out5);
}

// Round 6
// 64.302 us; speedup vs baseline: 3.2367x; 1.4731x over previous
//
#include <hip/hip_runtime.h>
#include <hip/hip_bf16.h>

#define BB 16
#define NC 64
#define NP 384
#define HH 128
#define CF 56
#define PFT 1280

typedef float f32x4 __attribute__((ext_vector_type(4)));
typedef __bf16 bf16x8 __attribute__((ext_vector_type(8)));
typedef unsigned short u16x8 __attribute__((ext_vector_type(8)));
typedef unsigned short u16x4 __attribute__((ext_vector_type(4)));

static __device__ __forceinline__ unsigned short f2bfu(float f){
  __bf16 h = (__bf16)f;
  return __builtin_bit_cast(unsigned short, h);
}
static __device__ __forceinline__ float bfu2f(unsigned short u){
  __bf16 h = __builtin_bit_cast(__bf16, u);
  return (float)h;
}

// ---------------- compound linear + LN -> bf16 (to ws) ----------------
__global__ __launch_bounds__(128) void k_comp_emb(
    const float* __restrict__ cf, const float* __restrict__ Wc,
    const float* __restrict__ bc, const float* __restrict__ lng,
    const float* __restrict__ lnb, unsigned short* __restrict__ c_ln){
  int row = blockIdx.x;
  int m = threadIdx.x;
  const float* cr = cf + row*CF;
  float acc = bc[m];
  #pragma unroll
  for (int k=0;k<CF;k++) acc += cr[k]*Wc[k*HH+m];
  float s=acc, s2=acc*acc;
  #pragma unroll
  for (int off=1; off<64; off<<=1){ s += __shfl_xor(s,off,64); s2 += __shfl_xor(s2,off,64); }
  __shared__ float red[4];
  int wid = m>>6;
  if ((m&63)==0){ red[wid*2]=s; red[wid*2+1]=s2; }
  __syncthreads();
  float S=red[0]+red[2], S2=red[1]+red[3];
  float mean = S*(1.0f/HH);
  float var  = S2*(1.0f/HH) - mean*mean;
  float rs = rsqrtf(var + 1e-5f);
  c_ln[row*HH+m] = f2bfu((acc-mean)*rs*lng[m] + lnb[m]);
}

// ---------------- Wp f32 [1280][128] -> WpT bf16 [128][1280] ----------------
__global__ __launch_bounds__(256) void k_wpt(const float* __restrict__ Wp,
                                             unsigned short* __restrict__ wpt){
  __shared__ unsigned short t[128][72];   // [col][k-chunk], padded
  int k0 = blockIdx.x*64;
  int tid = threadIdx.x;
  #pragma unroll
  for (int i=0;i<8;i++){
    int fi = tid + i*256;
    int k  = fi>>5;
    int c4 = (fi&31)*4;
    float4 v = *(const float4*)(Wp + (size_t)(k0+k)*HH + c4);
    t[c4+0][k]=f2bfu(v.x); t[c4+1][k]=f2bfu(v.y);
    t[c4+2][k]=f2bfu(v.z); t[c4+3][k]=f2bfu(v.w);
  }
  __syncthreads();
  #pragma unroll
  for (int i=0;i<4;i++){
    int ci = tid + i*256;
    int col = ci>>3, kb = ci&7;
    u16x8 v = *(const u16x8*)&t[col][kb*8];
    *(u16x8*)(wpt + (size_t)col*PFT + k0 + kb*8) = v;
  }
}

// ------- pocket GEMM [6144,1280]x[1280,128] + bias + LN -> bf16 p_ln -------
__global__ __launch_bounds__(256) void k_pock(
    const float* __restrict__ pf, const unsigned short* __restrict__ wpt,
    const float* __restrict__ bp, const float* __restrict__ lng,
    const float* __restrict__ lnb, unsigned short* __restrict__ p_ln){
  __shared__ __align__(16) unsigned short sA[2][32*64];
  __shared__ __align__(16) unsigned short sB[2][HH*64];
  __shared__ float sBp[HH], sG[HH], sBl[HH];
  int tid = threadIdx.x;
  int w = tid>>6, lane = tid&63, q = lane&15, gr = lane>>4;
  int pair = w>>1, rh = w&1;
  int tp = tid & 127;
  int row0 = blockIdx.x*32;
  if (tid < HH){ sBp[tid]=bp[tid]; sG[tid]=lng[tid]; sBl[tid]=lnb[tid]; }
  f32x4 acc[8];
  #pragma unroll
  for (int nt=0;nt<8;nt++) acc[nt]=(f32x4){0.f,0.f,0.f,0.f};
  char* A = (char*)&sA[pair][0];
  char* Bc = (char*)&sB[pair][0];
  int khalf0 = pair*640;
  int rowl = rh*16 + q;
  for (int ks=0; ks<10; ks++){
    int kbase = khalf0 + ks*64;
    __syncthreads();
    #pragma unroll
    for (int i=0;i<4;i++){
      int fi = tp + 128*i;
      int row = fi>>4;
      int k4  = (fi&15)*4;
      float4 v = *(const float4*)(pf + (size_t)(row0+row)*PFT + kbase + k4);
      u16x4 h = { f2bfu(v.x), f2bfu(v.y), f2bfu(v.z), f2bfu(v.w) };
      *(u16x4*)(A + row*128 + (((k4>>3)^(row&7))<<4) + ((k4&7)<<1)) = h;
    }
    #pragma unroll
    for (int i=0;i<8;i++){
      int bi = tp + 128*i;
      int col = bi>>3, kb = bi&7;
      u16x8 v = *(const u16x8*)(wpt + (size_t)col*PFT + kbase + kb*8);
      *(u16x8*)(Bc + col*128 + ((kb^(col&7))<<4)) = v;
    }
    __syncthreads();
    #pragma unroll
    for (int kk=0;kk<2;kk++){
      bf16x8 a = *(bf16x8*)(A + rowl*128 + (((kk*4+gr)^(rowl&7))<<4));
      #pragma unroll
      for (int nt=0;nt<8;nt++){
        int col = nt*16+q;
        bf16x8 b = *(bf16x8*)(Bc + col*128 + (((kk*4+gr)^(col&7))<<4));
        acc[nt] = __builtin_amdgcn_mfma_f32_16x16x32_bf16(a,b,acc[nt],0,0,0);
      }
    }
  }
  __syncthreads();
  float* comb = (float*)&sB[0][0];
  if (pair==1){
    #pragma unroll
    for (int nt=0;nt<8;nt++)
      #pragma unroll
      for (int r=0;r<4;r++)
        comb[(rh*16+gr*4+r)*HH + nt*16+q] = acc[nt][r];
  }
  __syncthreads();
  if (pair==0){
    float v[8][4];
    #pragma unroll
    for (int nt=0;nt<8;nt++){
      float bpv = sBp[nt*16+q];
      #pragma unroll
      for (int r=0;r<4;r++)
        v[nt][r] = acc[nt][r] + comb[(rh*16+gr*4+r)*HH + nt*16+q] + bpv;
    }
    #pragma unroll
    for (int r=0;r<4;r++){
      float s=0.f, s2=0.f;
      #pragma unroll
      for (int nt=0;nt<8;nt++){ s += v[nt][r]; s2 += v[nt][r]*v[nt][r]; }
      s  += __shfl_xor(s,1,64);  s2 += __shfl_xor(s2,1,64);
      s  += __shfl_xor(s,2,64);  s2 += __shfl_xor(s2,2,64);
      s  += __shfl_xor(s,4,64);  s2 += __shfl_xor(s2,4,64);
      s  += __shfl_xor(s,8,64);  s2 += __shfl_xor(s2,8,64);
      float mean = s*(1.0f/HH);
      float var  = s2*(1.0f/HH) - mean*mean;
      float rs   = rsqrtf(var + 1e-5f);
      int row = row0 + rh*16 + gr*4 + r;
      #pragma unroll
      for (int nt=0;nt<8;nt++){
        int col = nt*16+q;
        p_ln[(size_t)row*HH + col] = f2bfu((v[nt][r]-mean)*rs*sG[col] + sBl[col]);
      }
    }
  }
}

// ---------------- W1 (k,m) f32 -> W1^T (m,k) bf16 ----------------
__global__ void k_w1t(const float* __restrict__ W1, unsigned short* __restrict__ w1t){
  int idx = blockIdx.x*256+threadIdx.x;
  int k = idx>>7, m = idx&127;
  w1t[m*HH+k] = f2bfu(W1[idx]);
}

// ---- pairwise MLP v2: W1/c-frags register-resident, 12 i per block ----
// block = 256 thr (4 waves); wave w owns j-tile [w*16, w*16+16); grid 512.
__global__ __launch_bounds__(256,2) void k_pair(
    const unsigned short* __restrict__ c_ln, const unsigned short* __restrict__ p_ln,
    const unsigned short* __restrict__ w1t, const float* __restrict__ b1,
    const float* __restrict__ W2, const float* __restrict__ b2p,
    float* __restrict__ out3){
  __shared__ __align__(16) unsigned short sP[12*HH];   // 3 KB p rows
  int tid = threadIdx.x;
  int w = tid>>6, lane = tid&63, q = lane&15, gr = lane>>4;
  int bx = blockIdx.x;
  int b  = bx>>5;
  int i0 = (bx&31)*12;
  // stage p rows for this block's i-range
  {
    const u16x8* src = (const u16x8*)(p_ln + (size_t)(b*NP+i0)*HH);
    for (int c=tid; c<12*HH/8; c+=256) ((u16x8*)sP)[c] = src[c];
  }
  // c fragments (fixed across i): row j=w*16+q, k = kt*32+gr*8+e  -> f32
  float cf[4][8];
  {
    const unsigned short* cb = c_ln + (size_t)b*NC*HH + (size_t)(w*16+q)*HH + gr*8;
    #pragma unroll
    for (int kt=0;kt<4;kt++){
      u16x8 v = *(const u16x8*)(cb + kt*32);
      #pragma unroll
      for (int e=0;e<8;e++) cf[kt][e] = bfu2f(v[e]);
    }
  }
  // W1^T B-fragments (fixed for everything): lane holds W1T[nt*16+q][kt*32+gr*8..+8]
  bf16x8 w1f[4][8];
  #pragma unroll
  for (int kt=0;kt<4;kt++)
    #pragma unroll
    for (int nt=0;nt<8;nt++)
      w1f[kt][nt] = *(const bf16x8*)(w1t + (size_t)(nt*16+q)*HH + kt*32 + gr*8);
  float b1v[8], w2v[8];
  #pragma unroll
  for (int nt=0;nt<8;nt++){ b1v[nt]=b1[nt*16+q]; w2v[nt]=W2[nt*16+q]; }
  float b2 = b2p[0];
  __syncthreads();
  for (int ii=0; ii<12; ii++){
    f32x4 acc[8];
    #pragma unroll
    for (int nt=0;nt<8;nt++) acc[nt]=(f32x4){0.f,0.f,0.f,0.f};
    #pragma unroll
    for (int kt=0;kt<4;kt++){
      u16x8 pv = *(const u16x8*)&sP[ii*HH + kt*32 + gr*8];   // broadcast read
      bf16x8 a;
      #pragma unroll
      for (int e=0;e<8;e++) a[e] = (__bf16)(cf[kt][e]*bfu2f(pv[e]));
      #pragma unroll
      for (int nt=0;nt<8;nt++)
        acc[nt] = __builtin_amdgcn_mfma_f32_16x16x32_bf16(a, w1f[kt][nt], acc[nt], 0,0,0);
    }
    float part[4]={0.f,0.f,0.f,0.f};
    #pragma unroll
    for (int nt=0;nt<8;nt++)
      #pragma unroll
      for (int r=0;r<4;r++){
        float h = acc[nt][r] + b1v[nt];
        h = fmaxf(h, 0.f);
        part[r] += h*w2v[nt];
      }
    #pragma unroll
    for (int r=0;r<4;r++){
      part[r]+=__shfl_xor(part[r],1,16);
      part[r]+=__shfl_xor(part[r],2,16);
      part[r]+=__shfl_xor(part[r],4,16);
      part[r]+=__shfl_xor(part[r],8,16);
    }
    if (q==0){
      float4 o;
      o.x = 10.f/(1.f+expf(-(part[0]+b2)));
      o.y = 10.f/(1.f+expf(-(part[1]+b2)));
      o.z = 10.f/(1.f+expf(-(part[2]+b2)));
      o.w = 10.f/(1.f+expf(-(part[3]+b2)));
      *(float4*)(out3 + (size_t)(b*NP+i0+ii)*NC + w*16 + gr*4) = o;
    }
  }
}

// ---------------- coords + batch ids (float out) ----------------
__global__ void k_misc(const float* __restrict__ cc, float* __restrict__ out){
  int idx = blockIdx.x*256+threadIdx.x;
  if (idx < BB*NC*3){
    int bb = idx/(NC*3), rem = idx%(NC*3);
    float v = cc[(size_t)bb*(2+NC+NP)*3 + 3 + rem];
    out[idx] = (v/5.0f)*5.0f;
  }
  if (idx < BB*NC) out[BB*NC*3+idx] = (float)(idx>>6);
}

// ---------------- pc_dis + dis_map passthrough (float out) ----------------
__global__ void k_dis(const float* __restrict__ px, const float* __restrict__ cc,
                      const float* __restrict__ dm, float* __restrict__ out4,
                      float* __restrict__ out5){
  int idx = blockIdx.x*256+threadIdx.x;
  if (idx >= BB*NP*NC) return;
  int b = idx/(NP*NC), r = idx%(NP*NC), i = r>>6, j = r&63;
  const float* pp = px + ((size_t)b*NP+i)*3;
  const float* cp = cc + (size_t)b*(2+NC+NP)*3 + 3 + (size_t)j*3;
  float dx=pp[0]/5.0f-cp[0]/5.0f;
  float dy=pp[1]/5.0f-cp[1]/5.0f;
  float dz=pp[2]/5.0f-cp[2]/5.0f;
  float d = sqrtf(dx*dx+dy*dy+dz*dz)*5.0f;
  d = fminf(fmaxf(d,0.f),10.f);
  out4[idx]=d;
  out5[idx]=dm[idx];
}

extern "C" void kernel_launch(void* const* d_in, const int* in_sizes, int n_in,
                              void* d_out, int out_size, void* d_ws, size_t ws_size,
                              hipStream_t stream){
  const float* cf = (const float*)d_in[0];
  const float* pf = (const float*)d_in[1];
  const float* cc = (const float*)d_in[2];
  const float* px = (const float*)d_in[3];
  const float* dm = (const float*)d_in[4];
  const float* Wc = (const float*)d_in[5];
  const float* bc = (const float*)d_in[6];
  const float* Wp = (const float*)d_in[7];
  const float* bp = (const float*)d_in[8];
  const float* lng= (const float*)d_in[9];
  const float* lnb= (const float*)d_in[10];
  const float* W1 = (const float*)d_in[11];
  const float* b1 = (const float*)d_in[12];
  const float* W2 = (const float*)d_in[13];
  const float* b2 = (const float*)d_in[14];

  float* out = (float*)d_out;
  char* ws = (char*)d_ws;
  unsigned short* c_ln = (unsigned short*)ws;                      // 262144 B
  unsigned short* p_ln = (unsigned short*)(ws + 262144);           // 1572864 B
  unsigned short* w1t  = (unsigned short*)(ws + 262144 + 1572864); // 32768 B
  unsigned short* wpt  = (unsigned short*)(ws + 262144 + 1572864 + 32768); // 327680 B

  float* out1 = out;
  float* out3 = out + BB*NC*3 + BB*NC;
  float* out4 = out3 + BB*NP*NC;
  float* out5 = out4 + BB*NP*NC;

  hipLaunchKernelGGL(k_comp_emb, dim3(BB*NC),    dim3(128), 0, stream, cf, Wc, bc, lng, lnb, c_ln);
  hipLaunchKernelGGL(k_wpt,      dim3(PFT/64),   dim3(256), 0, stream, Wp, wpt);
  hipLaunchKernelGGL(k_pock,     dim3(BB*NP/32), dim3(256), 0, stream, pf, wpt, bp, lng, lnb, p_ln);
  hipLaunchKernelGGL(k_w1t,      dim3(64),       dim3(256), 0, stream, W1, w1t);
  hipLaunchKernelGGL(k_pair,     dim3(512),      dim3(256), 0, stream, c_ln, p_ln, w1t, b1, W2, b2, out3);
  hipLaunchKernelGGL(k_misc,     dim3(12),       dim3(256), 0, stream, cc, out1);
  hipLaunchKernelGGL(k_dis,      dim3(BB*NP*NC/256), dim3(256), 0, stream, px, cc, dm, out4, out5);
}

// Round 7
// 48.256 us; speedup vs baseline: 4.3129x; 1.3325x over previous
//
#include <hip/hip_runtime.h>
#include <hip/hip_bf16.h>

#define BB 16
#define NC 64
#define NP 384
#define HH 128
#define CF 56
#define PFT 1280

typedef float f32x4 __attribute__((ext_vector_type(4)));
typedef __bf16 bf16x8 __attribute__((ext_vector_type(8)));
typedef unsigned short u16x8 __attribute__((ext_vector_type(8)));
typedef unsigned short u16x4 __attribute__((ext_vector_type(4)));

static __device__ __forceinline__ unsigned short f2bfu(float f){
  __bf16 h = (__bf16)f;
  return __builtin_bit_cast(unsigned short, h);
}
static __device__ __forceinline__ float bfu2f(unsigned short u){
  __bf16 h = __builtin_bit_cast(__bf16, u);
  return (float)h;
}

// ---- k_prep: fused {WpT transpose | W1T | compound linear+LN | coords | dis} ----
// blocks [0,20): wpt ; [20,84): w1t ; [84,596): comp (2 rows each) ;
// [596,608): misc ; [608,2144): dis
__global__ __launch_bounds__(256) void k_prep(
    const float* __restrict__ cf, const float* __restrict__ Wc,
    const float* __restrict__ bc, const float* __restrict__ lng,
    const float* __restrict__ lnb, const float* __restrict__ Wp,
    const float* __restrict__ W1, const float* __restrict__ cc,
    const float* __restrict__ px, const float* __restrict__ dm,
    unsigned short* __restrict__ c_ln, unsigned short* __restrict__ wpt,
    unsigned short* __restrict__ w1t,
    float* __restrict__ out1, float* __restrict__ out4, float* __restrict__ out5){
  __shared__ unsigned short t[128][72];        // wpt transpose staging
  __shared__ float redc[2][2], redc2[2][2];    // comp LN reduce
  int bx = blockIdx.x;
  int tid = threadIdx.x;
  if (bx < 20){
    int k0 = bx*64;
    #pragma unroll
    for (int i=0;i<8;i++){
      int fi = tid + i*256;
      int k  = fi>>5;
      int c4 = (fi&31)*4;
      float4 v = *(const float4*)(Wp + (size_t)(k0+k)*HH + c4);
      t[c4+0][k]=f2bfu(v.x); t[c4+1][k]=f2bfu(v.y);
      t[c4+2][k]=f2bfu(v.z); t[c4+3][k]=f2bfu(v.w);
    }
    __syncthreads();
    #pragma unroll
    for (int i=0;i<4;i++){
      int ci = tid + i*256;
      int col = ci>>3, kb = ci&7;
      u16x8 v = *(const u16x8*)&t[col][kb*8];
      *(u16x8*)(wpt + (size_t)col*PFT + k0 + kb*8) = v;
    }
  } else if (bx < 84){
    int idx = (bx-20)*256+tid;
    int k = idx>>7, m = idx&127;
    w1t[m*HH+k] = f2bfu(W1[idx]);
  } else if (bx < 596){
    int rh = tid>>7, m = tid&127;
    int row = (bx-84)*2 + rh;
    const float* cr = cf + row*CF;
    float acc = bc[m];
    #pragma unroll
    for (int k=0;k<CF;k++) acc += cr[k]*Wc[k*HH+m];
    float s=acc, s2=acc*acc;
    #pragma unroll
    for (int off=1; off<64; off<<=1){ s += __shfl_xor(s,off,64); s2 += __shfl_xor(s2,off,64); }
    int wid = (tid>>6)&1;
    if ((m&63)==0){ redc[rh][wid]=s; redc2[rh][wid]=s2; }
    __syncthreads();
    float S=redc[rh][0]+redc[rh][1], S2=redc2[rh][0]+redc2[rh][1];
    float mean = S*(1.0f/HH);
    float var  = S2*(1.0f/HH) - mean*mean;
    float rs = rsqrtf(var + 1e-5f);
    c_ln[(size_t)row*HH+m] = f2bfu((acc-mean)*rs*lng[m] + lnb[m]);
  } else if (bx < 608){
    int idx = (bx-596)*256+tid;
    if (idx < BB*NC*3){
      int bb = idx/(NC*3), rem = idx%(NC*3);
      float v = cc[(size_t)bb*(2+NC+NP)*3 + 3 + rem];
      out1[idx] = (v/5.0f)*5.0f;
    }
    if (idx < BB*NC) out1[BB*NC*3+idx] = (float)(idx>>6);
  } else {
    int idx = (bx-608)*256+tid;
    int b = idx/(NP*NC), r = idx%(NP*NC), i = r>>6, j = r&63;
    const float* pp = px + ((size_t)b*NP+i)*3;
    const float* cp = cc + (size_t)b*(2+NC+NP)*3 + 3 + (size_t)j*3;
    float dx=pp[0]/5.0f-cp[0]/5.0f;
    float dy=pp[1]/5.0f-cp[1]/5.0f;
    float dz=pp[2]/5.0f-cp[2]/5.0f;
    float d = sqrtf(dx*dx+dy*dy+dz*dz)*5.0f;
    d = fminf(fmaxf(d,0.f),10.f);
    out4[idx]=d;
    out5[idx]=dm[idx];
  }
}

// ------- pocket GEMM + bias + LN -> bf16 p_ln ; reg-prefetch double-buffer -------
// BM=32, 4 waves: pair=w>>1 owns K-half; one barrier per K-step.
__global__ __launch_bounds__(256) void k_pock(
    const float* __restrict__ pf, const unsigned short* __restrict__ wpt,
    const float* __restrict__ bp, const float* __restrict__ lng,
    const float* __restrict__ lnb, unsigned short* __restrict__ p_ln){
  __shared__ __align__(16) unsigned short sA[2][2][32*64];   // [pair][buf]
  __shared__ __align__(16) unsigned short sB[2][2][HH*64];   // [pair][buf]
  __shared__ float sBp[HH], sG[HH], sBl[HH];
  int tid = threadIdx.x;
  int w = tid>>6, lane = tid&63, q = lane&15, gr = lane>>4;
  int pair = w>>1, rh = w&1;
  int tp = tid & 127;
  int row0 = blockIdx.x*32;
  if (tid < HH){ sBp[tid]=bp[tid]; sG[tid]=lng[tid]; sBl[tid]=lnb[tid]; }
  f32x4 acc[8];
  #pragma unroll
  for (int nt=0;nt<8;nt++) acc[nt]=(f32x4){0.f,0.f,0.f,0.f};
  int khalf0 = pair*640;
  int rowl = rh*16 + q;
  // per-thread staging coords
  int arow = tp>>2, ak4 = (tp&3)*16;         // rows 0..31, k4 in {0,16,32,48} (x4 floats)
  float4 ra[4]; u16x8 rb[8];
  // ---- load tile ks into registers ----
  #define LOADS(KS) {                                                        \
    int kbase = khalf0 + (KS)*64;                                            \
    _Pragma("unroll")                                                        \
    for (int i=0;i<4;i++)                                                    \
      ra[i] = *(const float4*)(pf + (size_t)(row0+arow)*PFT + kbase + ak4 + i*4); \
    _Pragma("unroll")                                                        \
    for (int i=0;i<8;i++){                                                   \
      int bi = tp + 128*i;                                                   \
      int col = bi>>3, kb = bi&7;                                            \
      rb[i] = *(const u16x8*)(wpt + (size_t)col*PFT + kbase + kb*8);         \
    }                                                                        \
  }
  #define WRITES(BUF) {                                                      \
    char* A = (char*)&sA[pair][BUF][0];                                      \
    char* Bc = (char*)&sB[pair][BUF][0];                                     \
    _Pragma("unroll")                                                        \
    for (int i=0;i<4;i++){                                                   \
      int k4 = ak4 + i*4;                                                    \
      u16x4 h = { f2bfu(ra[i].x), f2bfu(ra[i].y), f2bfu(ra[i].z), f2bfu(ra[i].w) }; \
      *(u16x4*)(A + arow*128 + (((k4>>3)^(arow&7))<<4) + ((k4&7)<<1)) = h;   \
    }                                                                        \
    _Pragma("unroll")                                                        \
    for (int i=0;i<8;i++){                                                   \
      int bi = tp + 128*i;                                                   \
      int col = bi>>3, kb = bi&7;                                            \
      *(u16x8*)(Bc + col*128 + ((kb^(col&7))<<4)) = rb[i];                   \
    }                                                                        \
  }
  LOADS(0)
  WRITES(0)
  int cur = 0;
  for (int ks=0; ks<10; ks++){
    if (ks<9) LOADS(ks+1)
    __syncthreads();
    char* A = (char*)&sA[pair][cur][0];
    char* Bc = (char*)&sB[pair][cur][0];
    #pragma unroll
    for (int kk=0;kk<2;kk++){
      bf16x8 a = *(bf16x8*)(A + rowl*128 + (((kk*4+gr)^(rowl&7))<<4));
      #pragma unroll
      for (int nt=0;nt<8;nt++){
        int col = nt*16+q;
        bf16x8 b = *(bf16x8*)(Bc + col*128 + (((kk*4+gr)^(col&7))<<4));
        acc[nt] = __builtin_amdgcn_mfma_f32_16x16x32_bf16(a,b,acc[nt],0,0,0);
      }
    }
    if (ks<9){ WRITES(cur^1) cur ^= 1; }
  }
  __syncthreads();
  float* comb = (float*)&sB[0][0][0];
  if (pair==1){
    #pragma unroll
    for (int nt=0;nt<8;nt++)
      #pragma unroll
      for (int r=0;r<4;r++)
        comb[(rh*16+gr*4+r)*HH + nt*16+q] = acc[nt][r];
  }
  __syncthreads();
  if (pair==0){
    float v[8][4];
    #pragma unroll
    for (int nt=0;nt<8;nt++){
      float bpv = sBp[nt*16+q];
      #pragma unroll
      for (int r=0;r<4;r++)
        v[nt][r] = acc[nt][r] + comb[(rh*16+gr*4+r)*HH + nt*16+q] + bpv;
    }
    #pragma unroll
    for (int r=0;r<4;r++){
      float s=0.f, s2=0.f;
      #pragma unroll
      for (int nt=0;nt<8;nt++){ s += v[nt][r]; s2 += v[nt][r]*v[nt][r]; }
      s  += __shfl_xor(s,1,64);  s2 += __shfl_xor(s2,1,64);
      s  += __shfl_xor(s,2,64);  s2 += __shfl_xor(s2,2,64);
      s  += __shfl_xor(s,4,64);  s2 += __shfl_xor(s2,4,64);
      s  += __shfl_xor(s,8,64);  s2 += __shfl_xor(s2,8,64);
      float mean = s*(1.0f/HH);
      float var  = s2*(1.0f/HH) - mean*mean;
      float rs   = rsqrtf(var + 1e-5f);
      int row = row0 + rh*16 + gr*4 + r;
      #pragma unroll
      for (int nt=0;nt<8;nt++){
        int col = nt*16+q;
        p_ln[(size_t)row*HH + col] = f2bfu((v[nt][r]-mean)*rs*sG[col] + sBl[col]);
      }
    }
  }
}

// ---- pairwise MLP v2: W1/c-frags register-resident, 12 i per block ----
__global__ __launch_bounds__(256,2) void k_pair(
    const unsigned short* __restrict__ c_ln, const unsigned short* __restrict__ p_ln,
    const unsigned short* __restrict__ w1t, const float* __restrict__ b1,
    const float* __restrict__ W2, const float* __restrict__ b2p,
    float* __restrict__ out3){
  __shared__ __align__(16) unsigned short sP[12*HH];
  int tid = threadIdx.x;
  int w = tid>>6, lane = tid&63, q = lane&15, gr = lane>>4;
  int bx = blockIdx.x;
  int b  = bx>>5;
  int i0 = (bx&31)*12;
  {
    const u16x8* src = (const u16x8*)(p_ln + (size_t)(b*NP+i0)*HH);
    for (int c=tid; c<12*HH/8; c+=256) ((u16x8*)sP)[c] = src[c];
  }
  float cf[4][8];
  {
    const unsigned short* cb = c_ln + (size_t)b*NC*HH + (size_t)(w*16+q)*HH + gr*8;
    #pragma unroll
    for (int kt=0;kt<4;kt++){
      u16x8 v = *(const u16x8*)(cb + kt*32);
      #pragma unroll
      for (int e=0;e<8;e++) cf[kt][e] = bfu2f(v[e]);
    }
  }
  bf16x8 w1f[4][8];
  #pragma unroll
  for (int kt=0;kt<4;kt++)
    #pragma unroll
    for (int nt=0;nt<8;nt++)
      w1f[kt][nt] = *(const bf16x8*)(w1t + (size_t)(nt*16+q)*HH + kt*32 + gr*8);
  float b1v[8], w2v[8];
  #pragma unroll
  for (int nt=0;nt<8;nt++){ b1v[nt]=b1[nt*16+q]; w2v[nt]=W2[nt*16+q]; }
  float b2 = b2p[0];
  __syncthreads();
  for (int ii=0; ii<12; ii++){
    f32x4 acc[8];
    #pragma unroll
    for (int nt=0;nt<8;nt++) acc[nt]=(f32x4){0.f,0.f,0.f,0.f};
    #pragma unroll
    for (int kt=0;kt<4;kt++){
      u16x8 pv = *(const u16x8*)&sP[ii*HH + kt*32 + gr*8];
      bf16x8 a;
      #pragma unroll
      for (int e=0;e<8;e++) a[e] = (__bf16)(cf[kt][e]*bfu2f(pv[e]));
      #pragma unroll
      for (int nt=0;nt<8;nt++)
        acc[nt] = __builtin_amdgcn_mfma_f32_16x16x32_bf16(a, w1f[kt][nt], acc[nt], 0,0,0);
    }
    float part[4]={0.f,0.f,0.f,0.f};
    #pragma unroll
    for (int nt=0;nt<8;nt++)
      #pragma unroll
      for (int r=0;r<4;r++){
        float h = acc[nt][r] + b1v[nt];
        h = fmaxf(h, 0.f);
        part[r] += h*w2v[nt];
      }
    #pragma unroll
    for (int r=0;r<4;r++){
      part[r]+=__shfl_xor(part[r],1,16);
      part[r]+=__shfl_xor(part[r],2,16);
      part[r]+=__shfl_xor(part[r],4,16);
      part[r]+=__shfl_xor(part[r],8,16);
    }
    if (q==0){
      float4 o;
      o.x = 10.f/(1.f+expf(-(part[0]+b2)));
      o.y = 10.f/(1.f+expf(-(part[1]+b2)));
      o.z = 10.f/(1.f+expf(-(part[2]+b2)));
      o.w = 10.f/(1.f+expf(-(part[3]+b2)));
      *(float4*)(out3 + (size_t)(b*NP+i0+ii)*NC + w*16 + gr*4) = o;
    }
  }
}

extern "C" void kernel_launch(void* const* d_in, const int* in_sizes, int n_in,
                              void* d_out, int out_size, void* d_ws, size_t ws_size,
                              hipStream_t stream){
  const float* cf = (const float*)d_in[0];
  const float* pf = (const float*)d_in[1];
  const float* cc = (const float*)d_in[2];
  const float* px = (const float*)d_in[3];
  const float* dm = (const float*)d_in[4];
  const float* Wc = (const float*)d_in[5];
  const float* bc = (const float*)d_in[6];
  const float* Wp = (const float*)d_in[7];
  const float* bp = (const float*)d_in[8];
  const float* lng= (const float*)d_in[9];
  const float* lnb= (const float*)d_in[10];
  const float* W1 = (const float*)d_in[11];
  const float* b1 = (const float*)d_in[12];
  const float* W2 = (const float*)d_in[13];
  const float* b2 = (const float*)d_in[14];

  float* out = (float*)d_out;
  char* ws = (char*)d_ws;
  unsigned short* c_ln = (unsigned short*)ws;                      // 262144 B
  unsigned short* p_ln = (unsigned short*)(ws + 262144);           // 1572864 B
  unsigned short* w1t  = (unsigned short*)(ws + 262144 + 1572864); // 32768 B
  unsigned short* wpt  = (unsigned short*)(ws + 262144 + 1572864 + 32768); // 327680 B

  float* out1 = out;
  float* out3 = out + BB*NC*3 + BB*NC;
  float* out4 = out3 + BB*NP*NC;
  float* out5 = out4 + BB*NP*NC;

  hipLaunchKernelGGL(k_prep, dim3(2144), dim3(256), 0, stream,
                     cf, Wc, bc, lng, lnb, Wp, W1, cc, px, dm,
                     c_ln, wpt, w1t, out1, out4, out5);
  hipLaunchKernelGGL(k_pock, dim3(BB*NP/32), dim3(256), 0, stream,
                     pf, wpt, bp, lng, lnb, p_ln);
  hipLaunchKernelGGL(k_pair, dim3(512), dim3(256), 0, stream,
                     c_ln, p_ln, w1t, b1, W2, b2, out3);
}

// Round 8
// 44.671 us; speedup vs baseline: 4.6590x; 1.0802x over previous
//
#include <hip/hip_runtime.h>
#include <hip/hip_bf16.h>

#define BB 16
#define NC 64
#define NP 384
#define HH 128
#define CF 56
#define PFT 1280

typedef float f32x4 __attribute__((ext_vector_type(4)));
typedef __bf16 bf16x8 __attribute__((ext_vector_type(8)));
typedef unsigned short u16x8 __attribute__((ext_vector_type(8)));
typedef unsigned short u16x4 __attribute__((ext_vector_type(4)));

static __device__ __forceinline__ unsigned short f2bfu(float f){
  __bf16 h = (__bf16)f;
  return __builtin_bit_cast(unsigned short, h);
}
static __device__ __forceinline__ float bfu2f(unsigned short u){
  __bf16 h = __builtin_bit_cast(__bf16, u);
  return (float)h;
}

// ---- k_prep: fused {WpT transpose | W1T | compound linear+LN | coords | dis} ----
__global__ __launch_bounds__(256) void k_prep(
    const float* __restrict__ cf, const float* __restrict__ Wc,
    const float* __restrict__ bc, const float* __restrict__ lng,
    const float* __restrict__ lnb, const float* __restrict__ Wp,
    const float* __restrict__ W1, const float* __restrict__ cc,
    const float* __restrict__ px, const float* __restrict__ dm,
    unsigned short* __restrict__ c_ln, unsigned short* __restrict__ wpt,
    unsigned short* __restrict__ w1t,
    float* __restrict__ out1, float* __restrict__ out4, float* __restrict__ out5){
  __shared__ unsigned short t[128][72];
  __shared__ float redc[2][2], redc2[2][2];
  int bx = blockIdx.x;
  int tid = threadIdx.x;
  if (bx < 20){
    int k0 = bx*64;
    #pragma unroll
    for (int i=0;i<8;i++){
      int fi = tid + i*256;
      int k  = fi>>5;
      int c4 = (fi&31)*4;
      float4 v = *(const float4*)(Wp + (size_t)(k0+k)*HH + c4);
      t[c4+0][k]=f2bfu(v.x); t[c4+1][k]=f2bfu(v.y);
      t[c4+2][k]=f2bfu(v.z); t[c4+3][k]=f2bfu(v.w);
    }
    __syncthreads();
    #pragma unroll
    for (int i=0;i<4;i++){
      int ci = tid + i*256;
      int col = ci>>3, kb = ci&7;
      u16x8 v = *(const u16x8*)&t[col][kb*8];
      *(u16x8*)(wpt + (size_t)col*PFT + k0 + kb*8) = v;
    }
  } else if (bx < 84){
    int idx = (bx-20)*256+tid;
    int k = idx>>7, m = idx&127;
    w1t[m*HH+k] = f2bfu(W1[idx]);
  } else if (bx < 596){
    int rh = tid>>7, m = tid&127;
    int row = (bx-84)*2 + rh;
    const float* cr = cf + row*CF;
    float acc = bc[m];
    #pragma unroll
    for (int k=0;k<CF;k++) acc += cr[k]*Wc[k*HH+m];
    float s=acc, s2=acc*acc;
    #pragma unroll
    for (int off=1; off<64; off<<=1){ s += __shfl_xor(s,off,64); s2 += __shfl_xor(s2,off,64); }
    int wid = (tid>>6)&1;
    if ((m&63)==0){ redc[rh][wid]=s; redc2[rh][wid]=s2; }
    __syncthreads();
    float S=redc[rh][0]+redc[rh][1], S2=redc2[rh][0]+redc2[rh][1];
    float mean = S*(1.0f/HH);
    float var  = S2*(1.0f/HH) - mean*mean;
    float rs = rsqrtf(var + 1e-5f);
    c_ln[(size_t)row*HH+m] = f2bfu((acc-mean)*rs*lng[m] + lnb[m]);
  } else if (bx < 608){
    int idx = (bx-596)*256+tid;
    if (idx < BB*NC*3){
      int bb = idx/(NC*3), rem = idx%(NC*3);
      float v = cc[(size_t)bb*(2+NC+NP)*3 + 3 + rem];
      out1[idx] = (v/5.0f)*5.0f;
    }
    if (idx < BB*NC) out1[BB*NC*3+idx] = (float)(idx>>6);
  } else {
    int idx = (bx-608)*256+tid;
    int b = idx/(NP*NC), r = idx%(NP*NC), i = r>>6, j = r&63;
    const float* pp = px + ((size_t)b*NP+i)*3;
    const float* cp = cc + (size_t)b*(2+NC+NP)*3 + 3 + (size_t)j*3;
    float dx=pp[0]/5.0f-cp[0]/5.0f;
    float dy=pp[1]/5.0f-cp[1]/5.0f;
    float dz=pp[2]/5.0f-cp[2]/5.0f;
    float d = sqrtf(dx*dx+dy*dy+dz*dz)*5.0f;
    d = fminf(fmaxf(d,0.f),10.f);
    out4[idx]=d;
    out5[idx]=dm[idx];
  }
}

// ---- k_main: fused {pocket GEMM+LN for 12 rows} + {pairwise MLP} per block ----
// 512 blocks x 256 thr; block (b = bx>>5, i0 = (bx&31)*12).
__global__ __launch_bounds__(256,2) void k_main(
    const float* __restrict__ pf, const unsigned short* __restrict__ wpt,
    const float* __restrict__ bp, const float* __restrict__ lng,
    const float* __restrict__ lnb,
    const unsigned short* __restrict__ c_ln, const unsigned short* __restrict__ w1t,
    const float* __restrict__ b1, const float* __restrict__ W2,
    const float* __restrict__ b2p, float* __restrict__ out3){
  __shared__ __align__(16) unsigned short sA[2][16*64];   // 2KB each, rows 12-15 zero
  __shared__ __align__(16) unsigned short sB[2][HH*64];   // 16KB each
  __shared__ __align__(16) float sPf[12*HH];              // 6KB: GEMM out -> LN -> p (f32)
  int tid = threadIdx.x;
  int w = tid>>6, lane = tid&63, q = lane&15, gr = lane>>4;
  int bx = blockIdx.x;
  int b  = bx>>5;
  int i0 = (bx&31)*12;
  size_t prow0 = (size_t)(b*NP + i0);
  // zero pad rows 12-15 of both A buffers
  *(unsigned short*)((char*)&sA[0][0] + 1536 + tid*2) = 0;
  *(unsigned short*)((char*)&sA[1][0] + 1536 + tid*2) = 0;
  // ---------------- phase 1: pocket GEMM (12 rows x 1280 x 128) ----------------
  f32x4 acc2[2];
  acc2[0]=(f32x4){0.f,0.f,0.f,0.f}; acc2[1]=(f32x4){0.f,0.f,0.f,0.f};
  int arow = tid>>4, ak4 = (tid&15)*4;      // A staging: 192 active threads
  float4 ra; u16x8 rb[4];
  #define LOADS1(KS) {                                                         \
    int kbase = (KS)*64;                                                       \
    if (arow < 12)                                                             \
      ra = *(const float4*)(pf + (prow0+arow)*PFT + kbase + ak4);              \
    _Pragma("unroll")                                                          \
    for (int i=0;i<4;i++){                                                     \
      int bi = tid + 256*i;                                                    \
      int col = bi>>3, kb = bi&7;                                              \
      rb[i] = *(const u16x8*)(wpt + (size_t)col*PFT + kbase + kb*8);           \
    }                                                                          \
  }
  #define WRITES1(BUF) {                                                       \
    char* A = (char*)&sA[BUF][0];                                              \
    char* Bc = (char*)&sB[BUF][0];                                             \
    if (arow < 12){                                                            \
      u16x4 h = { f2bfu(ra.x), f2bfu(ra.y), f2bfu(ra.z), f2bfu(ra.w) };        \
      *(u16x4*)(A + arow*128 + (((ak4>>3)^(arow&7))<<4) + ((ak4&7)<<1)) = h;   \
    }                                                                          \
    _Pragma("unroll")                                                          \
    for (int i=0;i<4;i++){                                                     \
      int bi = tid + 256*i;                                                    \
      int col = bi>>3, kb = bi&7;                                              \
      *(u16x8*)(Bc + col*128 + ((kb^(col&7))<<4)) = rb[i];                     \
    }                                                                          \
  }
  LOADS1(0)
  WRITES1(0)
  int cur = 0;
  for (int ks=0; ks<20; ks++){
    if (ks<19) LOADS1(ks+1)
    __syncthreads();
    char* A = (char*)&sA[cur][0];
    char* Bc = (char*)&sB[cur][0];
    #pragma unroll
    for (int kk=0;kk<2;kk++){
      bf16x8 a = *(bf16x8*)(A + q*128 + (((kk*4+gr)^(q&7))<<4));
      #pragma unroll
      for (int ct=0;ct<2;ct++){
        int col = w*32 + ct*16 + q;
        bf16x8 bfr = *(bf16x8*)(Bc + col*128 + (((kk*4+gr)^(col&7))<<4));
        acc2[ct] = __builtin_amdgcn_mfma_f32_16x16x32_bf16(a,bfr,acc2[ct],0,0,0);
      }
    }
    if (ks<19){ WRITES1(cur^1) cur ^= 1; }
  }
  // write GEMM result (+bias) to sPf
  __syncthreads();
  #pragma unroll
  for (int ct=0;ct<2;ct++){
    int col = w*32 + ct*16 + q;
    float bpv = bp[col];
    #pragma unroll
    for (int r=0;r<4;r++){
      int row = gr*4+r;
      if (row < 12) sPf[row*HH + col] = acc2[ct][r] + bpv;
    }
  }
  // load phase-2 invariants (hide under LN sync)
  float cfr[4][8];
  {
    const unsigned short* cb = c_ln + (size_t)b*NC*HH + (size_t)(w*16+q)*HH + gr*8;
    #pragma unroll
    for (int kt=0;kt<4;kt++){
      u16x8 v = *(const u16x8*)(cb + kt*32);
      #pragma unroll
      for (int e=0;e<8;e++) cfr[kt][e] = bfu2f(v[e]);
    }
  }
  bf16x8 w1f[4][8];
  #pragma unroll
  for (int kt=0;kt<4;kt++)
    #pragma unroll
    for (int nt=0;nt<8;nt++)
      w1f[kt][nt] = *(const bf16x8*)(w1t + (size_t)(nt*16+q)*HH + kt*32 + gr*8);
  float b1v[8], w2v[8];
  #pragma unroll
  for (int nt=0;nt<8;nt++){ b1v[nt]=b1[nt*16+q]; w2v[nt]=W2[nt*16+q]; }
  float b2 = b2p[0];
  __syncthreads();
  // ---------------- LN over the 12 rows (wave w -> rows w*3..w*3+2) ----------------
  {
    float g0 = lng[lane], g1 = lng[lane+64];
    float B0 = lnb[lane], B1 = lnb[lane+64];
    #pragma unroll
    for (int rr=0; rr<3; rr++){
      int row = w*3+rr;
      float a0 = sPf[row*HH + lane], a1 = sPf[row*HH + lane + 64];
      float s = a0+a1, s2 = a0*a0 + a1*a1;
      #pragma unroll
      for (int off=1; off<64; off<<=1){ s += __shfl_xor(s,off,64); s2 += __shfl_xor(s2,off,64); }
      float mean = s*(1.0f/HH);
      float var  = s2*(1.0f/HH) - mean*mean;
      float rs   = rsqrtf(var + 1e-5f);
      sPf[row*HH + lane]      = (a0-mean)*rs*g0 + B0;
      sPf[row*HH + lane + 64] = (a1-mean)*rs*g1 + B1;
    }
  }
  __syncthreads();
  // ---------------- phase 2: pairwise MLP over 12 i-rows ----------------
  for (int ii=0; ii<12; ii++){
    f32x4 acc[8];
    #pragma unroll
    for (int nt=0;nt<8;nt++) acc[nt]=(f32x4){0.f,0.f,0.f,0.f};
    #pragma unroll
    for (int kt=0;kt<4;kt++){
      f32x4 p0 = *(const f32x4*)&sPf[ii*HH + kt*32 + gr*8];
      f32x4 p1 = *(const f32x4*)&sPf[ii*HH + kt*32 + gr*8 + 4];
      bf16x8 a;
      #pragma unroll
      for (int e=0;e<4;e++) a[e]   = (__bf16)(cfr[kt][e]*p0[e]);
      #pragma unroll
      for (int e=0;e<4;e++) a[e+4] = (__bf16)(cfr[kt][e+4]*p1[e]);
      #pragma unroll
      for (int nt=0;nt<8;nt++)
        acc[nt] = __builtin_amdgcn_mfma_f32_16x16x32_bf16(a, w1f[kt][nt], acc[nt], 0,0,0);
    }
    float part[4]={0.f,0.f,0.f,0.f};
    #pragma unroll
    for (int nt=0;nt<8;nt++)
      #pragma unroll
      for (int r=0;r<4;r++){
        float h = acc[nt][r] + b1v[nt];
        h = fmaxf(h, 0.f);
        part[r] += h*w2v[nt];
      }
    #pragma unroll
    for (int r=0;r<4;r++){
      part[r]+=__shfl_xor(part[r],1,16);
      part[r]+=__shfl_xor(part[r],2,16);
      part[r]+=__shfl_xor(part[r],4,16);
      part[r]+=__shfl_xor(part[r],8,16);
    }
    if (q==0){
      float4 o;
      o.x = 10.f/(1.f+expf(-(part[0]+b2)));
      o.y = 10.f/(1.f+expf(-(part[1]+b2)));
      o.z = 10.f/(1.f+expf(-(part[2]+b2)));
      o.w = 10.f/(1.f+expf(-(part[3]+b2)));
      *(float4*)(out3 + (prow0+ii)*NC + w*16 + gr*4) = o;
    }
  }
}

extern "C" void kernel_launch(void* const* d_in, const int* in_sizes, int n_in,
                              void* d_out, int out_size, void* d_ws, size_t ws_size,
                              hipStream_t stream){
  const float* cf = (const float*)d_in[0];
  const float* pf = (const float*)d_in[1];
  const float* cc = (const float*)d_in[2];
  const float* px = (const float*)d_in[3];
  const float* dm = (const float*)d_in[4];
  const float* Wc = (const float*)d_in[5];
  const float* bc = (const float*)d_in[6];
  const float* Wp = (const float*)d_in[7];
  const float* bp = (const float*)d_in[8];
  const float* lng= (const float*)d_in[9];
  const float* lnb= (const float*)d_in[10];
  const float* W1 = (const float*)d_in[11];
  const float* b1 = (const float*)d_in[12];
  const float* W2 = (const float*)d_in[13];
  const float* b2 = (const float*)d_in[14];

  float* out = (float*)d_out;
  char* ws = (char*)d_ws;
  unsigned short* c_ln = (unsigned short*)ws;                      // 262144 B
  unsigned short* w1t  = (unsigned short*)(ws + 262144 + 1572864); // 32768 B
  unsigned short* wpt  = (unsigned short*)(ws + 262144 + 1572864 + 32768); // 327680 B

  float* out1 = out;
  float* out3 = out + BB*NC*3 + BB*NC;
  float* out4 = out3 + BB*NP*NC;
  float* out5 = out4 + BB*NP*NC;

  hipLaunchKernelGGL(k_prep, dim3(2144), dim3(256), 0, stream,
                     cf, Wc, bc, lng, lnb, Wp, W1, cc, px, dm,
                     c_ln, wpt, w1t, out1, out4, out5);
  hipLaunchKernelGGL(k_main, dim3(512), dim3(256), 0, stream,
                     pf, wpt, bp, lng, lnb, c_ln, w1t, b1, W2, b2, out3);
}